// Round 8
// baseline (107.101 us; speedup 1.0000x reference)
//
#include <hip/hip_runtime.h>
#include <hip/hip_fp16.h>

#define DIN 256
#define DOUT 64
#define SCAN_BLK 256
#define BUCKET_BITS 14
#define BUCKET (1 << BUCKET_BITS)   // 16384-entry LDS word array; packs 2 buckets (32768 nodes)
#define CHUNKS 64
#define BM 128

using half8 = __attribute__((ext_vector_type(8))) _Float16;
using f32x4 = __attribute__((ext_vector_type(4))) float;

// ---------------- histogram: packed-pair LDS counters -> u16 partials ----------------
// grid = (CHUNKS, 2, 2): y = bucket-pair (nodes y*32768 .. +32767), z = array (0 src, 1 dst)
// word w packs count(node pairbase+w) in low16, count(node pairbase+16384+w) in high16.
__global__ __launch_bounds__(256) void hist_kernel(
    const int* __restrict__ src, const int* __restrict__ dst,
    unsigned short* __restrict__ part, int n_nodes, int n_edges, int n_pad)
{
    __shared__ unsigned int cnt[BUCKET];
    const int c = blockIdx.x, p = blockIdx.y, a = blockIdx.z;
    const int* __restrict__ idx = a ? dst : src;
    const int pairbase = p << 15;

    for (int i = threadIdx.x; i < BUCKET; i += 256) cnt[i] = 0;
    __syncthreads();

    const int ebeg = (int)((long long)n_edges * c / CHUNKS);
    const int eend = (int)((long long)n_edges * (c + 1) / CHUNKS);
    const int nvec = (eend - ebeg) >> 2;
    const int4* idx4 = (const int4*)(idx + ebeg);
    for (int q = threadIdx.x; q < nvec; q += 256) {
        int4 e4 = idx4[q];
        unsigned u0 = (unsigned)(e4.x - pairbase);
        unsigned u1 = (unsigned)(e4.y - pairbase);
        unsigned u2 = (unsigned)(e4.z - pairbase);
        unsigned u3 = (unsigned)(e4.w - pairbase);
        if (u0 < 32768u) atomicAdd(&cnt[u0 & (BUCKET - 1)], 1u << ((u0 >> BUCKET_BITS) << 4));
        if (u1 < 32768u) atomicAdd(&cnt[u1 & (BUCKET - 1)], 1u << ((u1 >> BUCKET_BITS) << 4));
        if (u2 < 32768u) atomicAdd(&cnt[u2 & (BUCKET - 1)], 1u << ((u2 >> BUCKET_BITS) << 4));
        if (u3 < 32768u) atomicAdd(&cnt[u3 & (BUCKET - 1)], 1u << ((u3 >> BUCKET_BITS) << 4));
    }
    for (int e = ebeg + (nvec << 2) + threadIdx.x; e < eend; e += 256) {
        unsigned u = (unsigned)(idx[e] - pairbase);
        if (u < 32768u) atomicAdd(&cnt[u & (BUCKET - 1)], 1u << ((u >> BUCKET_BITS) << 4));
    }
    __syncthreads();

    unsigned short* row = part + (size_t)(a * CHUNKS + c) * n_pad;
    for (int w = threadIdx.x; w < BUCKET; w += 256) {
        unsigned v = cnt[w];
        int n0 = pairbase + w;
        int n1 = pairbase + BUCKET + w;
        if (n0 < n_nodes) row[n0] = (unsigned short)(v & 0xffffu);
        if (n1 < n_nodes) row[n1] = (unsigned short)(v >> 16);
    }
}

// ---------------- reduce partials -> outdeg/indeg, in-place prefix, bsum; extra blocks convert W ----------------
__global__ __launch_bounds__(256) void reduce_scan1_kernel(
    unsigned short* __restrict__ part, int* __restrict__ outdeg,
    int* __restrict__ indeg, int* __restrict__ bsum, int n_nodes, int n_pad,
    int nsb, const float* __restrict__ W, unsigned short* __restrict__ w16t)
{
    if (blockIdx.x >= nsb) {
        int idx = (blockIdx.x - nsb) * 256 + threadIdx.x;   // 0..16383
        int n = idx & 63, k = idx >> 6;
        __half v = __float2half(W[k * DOUT + n]);
        w16t[n * DIN + k] = *(unsigned short*)&v;
        return;
    }
    __shared__ int red[4];
    int i = blockIdx.x * 256 + threadIdx.x;
    int run = 0;
    if (i < n_nodes) {
        int s0 = 0;
        #pragma unroll
        for (int c = 0; c < CHUNKS; ++c) s0 += part[(size_t)c * n_pad + i];
        outdeg[i] = s0;
        #pragma unroll
        for (int c = 0; c < CHUNKS; ++c) {
            size_t off = (size_t)(CHUNKS + c) * n_pad + i;
            int t = part[off];
            part[off] = (unsigned short)run;
            run += t;
        }
        indeg[i] = run;
    }
    int v = run;
    #pragma unroll
    for (int off = 32; off >= 1; off >>= 1)
        v += __shfl_down(v, off, 64);
    if ((threadIdx.x & 63) == 0) red[threadIdx.x >> 6] = v;
    __syncthreads();
    if (threadIdx.x == 0)
        bsum[blockIdx.x] = red[0] + red[1] + red[2] + red[3];
}

// ---------------- emit rowptr; every block redundantly scans bsum in LDS ----------------
__global__ __launch_bounds__(SCAN_BLK) void emit_kernel(
    const int* __restrict__ indeg, const int* __restrict__ bsum,
    int* __restrict__ rowptr, int n, int n_edges, int nsb)
{
    __shared__ int bs[256];
    __shared__ int s[SCAN_BLK];
    int t = threadIdx.x;

    // scan the block sums (nsb <= 256)
    bs[t] = (t < nsb) ? bsum[t] : 0;
    __syncthreads();
    for (int off = 1; off < 256; off <<= 1) {
        int u = 0;
        if (t >= off) u = bs[t - off];
        __syncthreads();
        if (t >= off) bs[t] += u;
        __syncthreads();
    }
    int boff_blk = (blockIdx.x == 0) ? 0 : bs[blockIdx.x - 1];

    int idx = blockIdx.x * SCAN_BLK + t;
    int v = (idx < n) ? indeg[idx] : 0;
    s[t] = v;
    __syncthreads();
    for (int off = 1; off < SCAN_BLK; off <<= 1) {
        int u = 0;
        if (t >= off) u = s[t - off];
        __syncthreads();
        if (t >= off) s[t] += u;
        __syncthreads();
    }
    if (idx < n) rowptr[idx] = boff_blk + s[t] - v;
    if (idx == 0) rowptr[n] = n_edges;
}

// ---------------- CSR fill via LDS cursor multisplit (u16 col) ----------------
__global__ __launch_bounds__(256) void fill_kernel(
    const int* __restrict__ src, const int* __restrict__ dst,
    const unsigned short* __restrict__ part, const int* __restrict__ rowptr,
    unsigned short* __restrict__ col, int n_nodes, int n_edges, int n_pad)
{
    __shared__ int cur[BUCKET];
    const int c = blockIdx.x, b = blockIdx.y;
    const int base = b << BUCKET_BITS;
    const int lim = min(BUCKET, n_nodes - base);

    const unsigned short* prow = part + (size_t)(CHUNKS + c) * n_pad + base;
    const int* rp = rowptr + base;
    for (int i = threadIdx.x; i < lim; i += 256)
        cur[i] = rp[i] + (int)prow[i];
    __syncthreads();

    const int ebeg = (int)((long long)n_edges * c / CHUNKS);
    const int eend = (int)((long long)n_edges * (c + 1) / CHUNKS);
    const int nvec = (eend - ebeg) >> 2;
    const int4* dst4 = (const int4*)(dst + ebeg);
    const int4* src4 = (const int4*)(src + ebeg);
    for (int q = threadIdx.x; q < nvec; q += 256) {
        int4 d4 = dst4[q];
        int4 s4 = src4[q];
        unsigned v0 = (unsigned)(d4.x - base);
        unsigned v1 = (unsigned)(d4.y - base);
        unsigned v2 = (unsigned)(d4.z - base);
        unsigned v3 = (unsigned)(d4.w - base);
        if (v0 < (unsigned)BUCKET) col[atomicAdd(&cur[v0], 1)] = (unsigned short)s4.x;
        if (v1 < (unsigned)BUCKET) col[atomicAdd(&cur[v1], 1)] = (unsigned short)s4.y;
        if (v2 < (unsigned)BUCKET) col[atomicAdd(&cur[v2], 1)] = (unsigned short)s4.z;
        if (v3 < (unsigned)BUCKET) col[atomicAdd(&cur[v3], 1)] = (unsigned short)s4.w;
    }
    for (int e = ebeg + (nvec << 2) + threadIdx.x; e < eend; e += 256) {
        unsigned v = (unsigned)(dst[e] - base);
        if (v < (unsigned)BUCKET) col[atomicAdd(&cur[v], 1)] = (unsigned short)src[e];
    }
}

// ---------------- MFMA GEMM: h (two fp16 column-planes) = (x * norm_src) @ W ----------------
__global__ __launch_bounds__(256) void gemm_mfma_kernel(
    const float* __restrict__ x, const unsigned short* __restrict__ w16t,
    const int* __restrict__ outdeg, __half* __restrict__ h,
    int n_nodes, size_t plane_elems)
{
    __shared__ unsigned char Abuf[BM * 128];   // [128 rows][64 halves = 128 B], swizzled
    __shared__ unsigned char Bbuf[64 * 512];   // [64 cols][256 halves = 512 B], swizzled

    const int tid = threadIdx.x;
    const int r0 = blockIdx.x * BM;
    const int w = tid >> 6;
    const int lane = tid & 63;
    const int l16 = lane & 15;
    const int kg = lane >> 4;

    {
        const uint4* srcB = (const uint4*)w16t;
        for (int u = tid; u < 64 * 32; u += 256) {
            int c = u >> 5, q = u & 31;
            uint4 v = srcB[u];
            int byte = (c << 9) + (q << 4);
            byte ^= ((c & 7) << 4);
            *(uint4*)(Bbuf + byte) = v;
        }
    }

    f32x4 acc[2][4] = {{{0.f,0.f,0.f,0.f}}};

    for (int k0 = 0; k0 < 4; ++k0) {
        if (k0) __syncthreads();
        for (int u = tid; u < BM * 16; u += 256) {
            int row = u >> 4, fq = u & 15;
            int grow = r0 + row;
            float4 v = make_float4(0.f, 0.f, 0.f, 0.f);
            if (grow < n_nodes)
                v = *(const float4*)(&x[(size_t)grow * DIN + (k0 << 6) + (fq << 2)]);
            __half2 p0 = __floats2half2_rn(v.x, v.y);
            __half2 p1 = __floats2half2_rn(v.z, v.w);
            uint2 wv;
            wv.x = *(unsigned int*)&p0;
            wv.y = *(unsigned int*)&p1;
            int byte = (row << 7) + (fq << 3);
            byte ^= ((row & 7) << 4);
            *(uint2*)(Abuf + byte) = wv;
        }
        __syncthreads();

        #pragma unroll
        for (int ks = 0; ks < 2; ++ks) {
            half8 a[2], b[4];
            #pragma unroll
            for (int rt = 0; rt < 2; ++rt) {
                int row = (w << 5) + (rt << 4) + l16;
                int byte = (row << 7) + (ks << 6) + (kg << 4);
                byte ^= ((row & 7) << 4);
                a[rt] = *(const half8*)(Abuf + byte);
            }
            #pragma unroll
            for (int ct = 0; ct < 4; ++ct) {
                int c = (ct << 4) + l16;
                int byte = (c << 9) + (k0 << 7) + (ks << 6) + (kg << 4);
                byte ^= ((c & 7) << 4);
                b[ct] = *(const half8*)(Bbuf + byte);
            }
            #pragma unroll
            for (int rt = 0; rt < 2; ++rt)
                #pragma unroll
                for (int ct = 0; ct < 4; ++ct)
                    acc[rt][ct] = __builtin_amdgcn_mfma_f32_16x16x32_f16(a[rt], b[ct], acc[rt][ct], 0, 0, 0);
        }
    }

    #pragma unroll
    for (int rt = 0; rt < 2; ++rt) {
        #pragma unroll
        for (int reg = 0; reg < 4; ++reg) {
            int grow = r0 + (w << 5) + (rt << 4) + (kg << 2) + reg;
            if (grow < n_nodes) {
                float ns = rsqrtf(fmaxf((float)outdeg[grow], 1.0f));
                #pragma unroll
                for (int ct = 0; ct < 4; ++ct) {
                    int colp = ((ct & 1) << 4) + l16;
                    __half* hp = h + (size_t)(ct >> 1) * plane_elems + ((size_t)grow << 5) + colp;
                    *hp = __float2half(acc[rt][ct][reg] * ns);
                }
            }
        }
    }
}

// ---------------- gather both planes (grid.y = plane): wave per dst node, 8 edges/iter ----------------
__global__ __launch_bounds__(256) void gather_kernel(
    const __half* __restrict__ h, const int* __restrict__ rowptr,
    const unsigned short* __restrict__ col, const float* __restrict__ bias,
    float* __restrict__ out, int n_nodes, size_t plane_elems)
{
    int wid = (blockIdx.x * blockDim.x + threadIdx.x) >> 6;
    int lane = threadIdx.x & 63;
    if (wid >= n_nodes) return;
    const int plane = blockIdx.y;
    const int g = lane >> 3, l8 = lane & 7;

    const int beg = rowptr[wid];
    const int end = rowptr[wid + 1];
    const int deg = end - beg;

    const char* hbase = (const char*)(h + (size_t)plane * plane_elems) + (l8 << 3);

    float4 acc = make_float4(0.f, 0.f, 0.f, 0.f);
    #pragma unroll 2
    for (int i = beg + g; i < end; i += 8) {
        int s = col[i];
        uint2 v = *(const uint2*)(hbase + ((size_t)s << 6));
        __half2 p0 = *(__half2*)&v.x;
        __half2 p1 = *(__half2*)&v.y;
        float2 a = __half22float2(p0);
        float2 b2 = __half22float2(p1);
        acc.x += a.x; acc.y += a.y; acc.z += b2.x; acc.w += b2.y;
    }

    #pragma unroll
    for (int d = 8; d <= 32; d <<= 1) {
        acc.x += __shfl_xor(acc.x, d, 64);
        acc.y += __shfl_xor(acc.y, d, 64);
        acc.z += __shfl_xor(acc.z, d, 64);
        acc.w += __shfl_xor(acc.w, d, 64);
    }

    if (g == 0) {
        float nd = rsqrtf(fmaxf((float)deg, 1.0f));
        int c0 = (plane << 5) + (l8 << 2);
        float4 bb = *(const float4*)(&bias[c0]);
        float4 o;
        o.x = fmaxf(fmaf(acc.x, nd, bb.x), 0.f);
        o.y = fmaxf(fmaf(acc.y, nd, bb.y), 0.f);
        o.z = fmaxf(fmaf(acc.z, nd, bb.z), 0.f);
        o.w = fmaxf(fmaf(acc.w, nd, bb.w), 0.f);
        *(float4*)(&out[((size_t)wid << 6) + c0]) = o;
    }
}

extern "C" void kernel_launch(void* const* d_in, const int* in_sizes, int n_in,
                              void* d_out, int out_size, void* d_ws, size_t ws_size,
                              hipStream_t stream) {
    const float* x   = (const float*)d_in[0];
    const float* W   = (const float*)d_in[1];
    const float* b   = (const float*)d_in[2];
    const int*   src = (const int*)d_in[3];
    const int*   dst = (const int*)d_in[4];
    float* out = (float*)d_out;

    const int n_nodes = in_sizes[0] / DIN;   // 50000
    const int n_edges = in_sizes[3];         // 800000
    const int nsb = (n_nodes + SCAN_BLK - 1) / SCAN_BLK;         // 196
    const int nbuck = (n_nodes + BUCKET - 1) >> BUCKET_BITS;     // 4
    const int npair = (nbuck + 1) >> 1;                          // 2 bucket-pairs
    const int n_pad = ((n_nodes + 63) / 64) * 64;                // 50048
    const size_t plane_elems = (size_t)n_pad * 32;               // halves per plane

    // workspace layout
    int* outdeg = (int*)d_ws;                   // n
    int* indeg  = outdeg + n_nodes;             // n
    int* rowptr = indeg + n_nodes;              // n+1
    int* bsum   = rowptr + n_nodes + 1;         // 256
    int* w16t_i = bsum + 256;                   // 8192 ints = 16384 halves
    unsigned short* col = (unsigned short*)(w16t_i + 8192);  // n_edges u16
    size_t col_bytes = ((size_t)n_edges * 2 + 63) / 64 * 64;
    size_t base = (size_t)((char*)col - (char*)d_ws) + col_bytes;
    unsigned short* part = (unsigned short*)((char*)d_ws + base);       // 2*CHUNKS*n_pad u16
    size_t h_off = base + ((size_t)2 * CHUNKS * n_pad * 2 + 63) / 64 * 64;
    __half* h = (__half*)((char*)d_ws + h_off);                         // 2 planes x n_pad x 32
    unsigned short* w16t = (unsigned short*)w16t_i;

    hist_kernel<<<dim3(CHUNKS, npair, 2), 256, 0, stream>>>(src, dst, part, n_nodes, n_edges, n_pad);
    reduce_scan1_kernel<<<nsb + 64, 256, 0, stream>>>(part, outdeg, indeg, bsum, n_nodes, n_pad, nsb, W, w16t);
    emit_kernel<<<nsb, SCAN_BLK, 0, stream>>>(indeg, bsum, rowptr, n_nodes, n_edges, nsb);
    fill_kernel<<<dim3(CHUNKS, nbuck), 256, 0, stream>>>(src, dst, part, rowptr, col, n_nodes, n_edges, n_pad);
    gemm_mfma_kernel<<<(n_nodes + BM - 1) / BM, 256, 0, stream>>>(x, w16t, outdeg, h, n_nodes, plane_elems);
    gather_kernel<<<dim3(((size_t)n_nodes * 64 + 255) / 256, 2), 256, 0, stream>>>(h, rowptr, col, b, out, n_nodes, plane_elems);
}